// Round 18
// baseline (107.920 us; speedup 1.0000x reference)
//
#include <hip/hip_runtime.h>
#include <hip/hip_bf16.h>

#define NPOS 131072   // 32*64*64 positions per batch

typedef __attribute__((ext_vector_type(8))) short short8;
typedef __attribute__((ext_vector_type(4))) float floatx4;
typedef unsigned int uint32;

__device__ __forceinline__ unsigned short bf16b(float v) {
    __hip_bfloat16 h = __float2bfloat16(v);
    return __builtin_bit_cast(unsigned short, h);
}
// inline-asm pack: ONLY for values destined to LDS/global (never straight to MFMA)
__device__ __forceinline__ uint32 cvtpk(float lo, float hi) {
    uint32 r;
    asm("v_cvt_pk_bf16_f32 %0, %1, %2" : "=v"(r) : "v"(lo), "v"(hi));
    return r;
}
// cheap rounded pack (round-half-up): valid for finite non-NaN inputs (P = exp2 of
// bounded logits). 5 VALU ops vs ~12-15 for 2x RNE __float2bfloat16. Compiler-visible.
__device__ __forceinline__ uint32 pkr(float lo, float hi) {
    uint32 ul = __builtin_bit_cast(uint32, lo) + 0x8000u;
    uint32 uh = __builtin_bit_cast(uint32, hi) + 0x8000u;
    return (uh & 0xFFFF0000u) | (ul >> 16);
}
#if __has_builtin(__builtin_amdgcn_exp2f)
#define EXP2(x) __builtin_amdgcn_exp2f(x)
#else
#define EXP2(x) exp2f(x)
#endif
#if __has_builtin(__builtin_amdgcn_rcpf)
#define RCPF(x) __builtin_amdgcn_rcpf(x)
#else
#define RCPF(x) (1.0f / (x))
#endif

// 16x16x32 operand with logical k=lg*4+e at element slots e=0..3, zeros at e=4..7.
__device__ __forceinline__ short8 emb4(uint32 w0, uint32 w1) {
    union { uint32 u[4]; short8 s; } z;
    z.u[0] = w0; z.u[1] = w1; z.u[2] = 0; z.u[3] = 0;
    return z.s;
}
// alias-safe 8-byte load (memcpy => ds_read_b64 / global_load_dwordx2)
__device__ __forceinline__ short8 emb4m(const unsigned short* p) {
    uint32 w[2];
    __builtin_memcpy(w, p, 8);
    return emb4(w[0], w[1]);
}

// ---------------- K0: wq -> bf16*QS, wout -> bf16 ----------------
__global__ void k_prep_w(const float* __restrict__ wq, const float* __restrict__ wout,
                         unsigned short* __restrict__ wqb, unsigned short* __restrict__ woutb) {
    const float QS = 0.36067376022224085f;   // 0.25 * log2(e)
    int gid = blockIdx.x * 256 + threadIdx.x;
    wqb[gid]   = bf16b(wq[gid] * QS);
    woutb[gid] = bf16b(wout[gid]);
}

// ---------------- K1: wkv[oc][ic][term] f32 -> wtb[ic][oc][term] bf16 ----------------
__global__ void k_prep_wkvb(const float* __restrict__ wkv, unsigned short* __restrict__ wtb) {
    int gid = blockIdx.x * 256 + threadIdx.x;
    int ic = gid >> 14;
    int oc = (gid >> 7) & 127;
    float4 v = *(const float4*)(wkv + ((size_t)(oc * 64 + ic)) * 512 + (size_t)(gid & 127) * 4);
    uint32* dst = (uint32*)(wtb + (size_t)gid * 4);
    dst[0] = cvtpk(v.x, v.y);
    dst[1] = cvtpk(v.z, v.w);
}

// ---------------- K2: conv as bf16 MFMA GEMM, 2 ic per block (R13 conv, exonerated) ----------------
// grid 256: icg = bid&31 (XCD-affine), b = (bid>>5)&1, pz = bid>>6; 256 thr (4 waves)
__global__ __launch_bounds__(256) void k_conv_mfma(const float* __restrict__ x,
                                                   const unsigned short* __restrict__ wtb,
                                                   float* __restrict__ partial) {
    __shared__ __align__(16) unsigned short As[64 * 72];
    __shared__ __align__(16) unsigned short Bs[128 * 72];
    const int bid = blockIdx.x;
    const int icg = bid & 31;
    const int b  = (bid >> 5) & 1;
    const int pz = bid >> 6;
    const int tid = threadIdx.x;
    const int lane = tid & 63, wv = tid >> 6;
    const int lc = lane & 15, lg = lane >> 4;

    floatx4 acc[4][2];
#pragma unroll
    for (int mt = 0; mt < 4; ++mt)
#pragma unroll
        for (int n = 0; n < 2; ++n) acc[mt][n] = {0.f, 0.f, 0.f, 0.f};

#pragma unroll 1
    for (int s = 0; s < 2; ++s) {
        const int ic = icg * 2 + s;
        const float* xp = x + ((size_t)b * 64 + ic) * NPOS + (size_t)pz * 8 * 4096;
        const unsigned short* wp = wtb + (size_t)ic * 128 * 512;

        for (int rz = 0; rz < 8; ++rz) {
            __syncthreads();
            const float* plane = xp + (size_t)rz * 4096;
#pragma unroll
            for (int t2 = 0; t2 < 4; ++t2) {
                int e = (t2 * 256 + tid) * 4;
                int y = e >> 6, x0 = e & 63;
                int p = ((y >> 3) << 3) + (x0 >> 3);
                int k = ((y & 7) << 3) + (x0 & 7);
                float4 v = *(const float4*)(plane + e);
                uint32* dst = (uint32*)&As[p * 72 + k];
                dst[0] = cvtpk(v.x, v.y);
                dst[1] = cvtpk(v.z, v.w);
            }
            {
                int oc = tid >> 1, hf = tid & 1;
                const uint4* src = (const uint4*)(wp + (size_t)oc * 512 + rz * 64 + hf * 32);
                uint4* dst = (uint4*)&Bs[oc * 72 + hf * 32];
#pragma unroll
                for (int r = 0; r < 4; ++r) dst[r] = src[r];
            }
            __syncthreads();
#pragma unroll
            for (int ks = 0; ks < 2; ++ks) {
                short8 bb0 = *(const short8*)&Bs[((wv * 2 + 0) * 16 + lc) * 72 + ks * 32 + lg * 8];
                short8 bb1 = *(const short8*)&Bs[((wv * 2 + 1) * 16 + lc) * 72 + ks * 32 + lg * 8];
#pragma unroll
                for (int mt = 0; mt < 4; ++mt) {
                    short8 a = *(const short8*)&As[(mt * 16 + lc) * 72 + ks * 32 + lg * 8];
                    acc[mt][0] = __builtin_amdgcn_mfma_f32_16x16x32_bf16(a, bb0, acc[mt][0], 0, 0, 0);
                    acc[mt][1] = __builtin_amdgcn_mfma_f32_16x16x32_bf16(a, bb1, acc[mt][1], 0, 0, 0);
                }
            }
        }
    }
    float* pb = partial + (((size_t)icg * 2 + b) * 256 + pz * 64) * 128;
#pragma unroll
    for (int mt = 0; mt < 4; ++mt)
#pragma unroll
        for (int ntl = 0; ntl < 2; ++ntl) {
            int oc = (wv * 2 + ntl) * 16 + lc;
#pragma unroll
            for (int r = 0; r < 4; ++r) {
                int m = mt * 16 + lg * 4 + r;
                pb[(size_t)m * 128 + oc] = acc[mt][ntl][r];
            }
        }
}

// ---------------- K3: reduce over 32 ic-groups; K -> [b][h][256][16], V -> [b][h][16][256] ----------------
__global__ void k_reduce(const float* __restrict__ partial,
                         unsigned short* __restrict__ kt, unsigned short* __restrict__ vt) {
    int gid = blockIdx.x * 256 + threadIdx.x;
    int oc = gid & 127;
    int bp = gid >> 7;          // b*256 + j
    int b = bp >> 8;
    int j = bp & 255;
    const float* p = partial + (size_t)bp * 128 + oc;
    float s = 0.f;
#pragma unroll 8
    for (int ic = 0; ic < 32; ++ic) s += p[(size_t)ic * 65536];
    int h = (oc & 63) >> 4, i = oc & 15;
    if (oc < 64)
        kt[(((size_t)b * 4 + h) * 256 + j) * 16 + i] = bf16b(s);
    else
        vt[(((size_t)b * 4 + h) * 16 + i) * 256 + j] = bf16b(s);
}

// ---------------- K4: R17 attn with cheap rounded P-pack (pkr) ----------------
// grid 4096 = b(2) x 2048 n-blocks of 64; 256 thr; wave wv = head wv, 64 queries/wave.
__global__ __launch_bounds__(256, 5) void k_attn14(
    const float* __restrict__ x, const unsigned short* __restrict__ wqb,
    const unsigned short* __restrict__ woutb, const unsigned short* __restrict__ kt,
    const unsigned short* __restrict__ vt, float* __restrict__ out)
{
    __shared__ __align__(16) unsigned short s_at[64 * 72];    // x^T then att [n][c]
    __shared__ __align__(16) unsigned short s_q[4][64 * 20];  // per-wave Q [n][i] stride 20
    __shared__ float s_l[4][64];

    const int tid = threadIdx.x;
    const int b = blockIdx.x >> 11;
    const int n_base = (blockIdx.x & 2047) << 6;
    const int lane = tid & 63;
    const int wv = tid >> 6;     // head index
    const int lc = lane & 15;
    const int lg = lane >> 4;

    unsigned short* qs = s_q[wv];

    // ---- stage x^T [64][72] cooperatively (verified) ----
    {
        int n_l = tid & 63;
        int c0  = (tid >> 6) * 16;
        const float* xb = x + ((size_t)b << 23) + n_base + n_l;
        uint32* xrow = (uint32*)&s_at[n_l * 72 + c0];
#pragma unroll
        for (int r = 0; r < 8; ++r) {
            float v0 = xb[(size_t)(c0 + 2 * r) << 17];
            float v1 = xb[(size_t)(c0 + 2 * r + 1) << 17];
            xrow[r] = cvtpk(v0, v1);
        }
    }
    __syncthreads();   // B1: x^T staged

    // ---- Q-proj (verified, store stride 20) ----
#pragma unroll
    for (int t = 0; t < 4; ++t) {
        floatx4 c = {0.f, 0.f, 0.f, 0.f};
#pragma unroll
        for (int ks = 0; ks < 2; ++ks) {
            short8 a = *(const short8*)&s_at[(t * 16 + lc) * 72 + ks * 32 + lg * 8];
            short8 bfull;
            __builtin_memcpy(&bfull, wqb + (wv * 16 + lc) * 64 + ks * 32 + lg * 8, 16);
            c = __builtin_amdgcn_mfma_f32_16x16x32_bf16(a, bfull, c, 0, 0, 0);
        }
#pragma unroll
        for (int r = 0; r < 4; ++r)
            qs[(t * 16 + lg * 4 + r) * 20 + lc] = bf16b(c[r]);
    }

    __syncthreads();   // B2: fences transposed Q writes->reads AND Q-proj s_at reads

    // ---- hoist Q B-frags AFTER the barrier: logical k=i=lg*4+e via emb4 ----
    short8 qf[4];
#pragma unroll
    for (int t = 0; t < 4; ++t)
        qf[t] = emb4m(&qs[(t * 16 + lc) * 20 + lg * 4]);

    // ---- head loop: 16 j-tiles of 16 keys, all-register P ----
    const unsigned short* kh = kt + (((size_t)b * 4 + wv) << 12);
    const unsigned short* vh = vt + (((size_t)b * 4 + wv) << 12);
    float lp[4] = {0.f, 0.f, 0.f, 0.f};
    floatx4 pv[4];
#pragma unroll
    for (int t = 0; t < 4; ++t) pv[t] = {0.f, 0.f, 0.f, 0.f};

#pragma unroll 4
    for (int jt = 0; jt < 16; ++jt) {
        const int j0 = jt * 16;
        short8 kf = emb4m(kh + (size_t)(j0 + lc) * 16 + lg * 4);
        short8 vf = emb4m(vh + (size_t)lc * 256 + j0 + lg * 4);
#pragma unroll
        for (int t = 0; t < 4; ++t) {
            floatx4 z = {0.f, 0.f, 0.f, 0.f};
            floatx4 c = __builtin_amdgcn_mfma_f32_16x16x32_bf16(kf, qf[t], z, 0, 0, 0); // S^T: n=lc, j=lg*4+r
            float p0 = EXP2(c[0]), p1 = EXP2(c[1]), p2 = EXP2(c[2]), p3 = EXP2(c[3]);
            lp[t] += (p0 + p1) + (p2 + p3);
            short8 pa = emb4(pkr(p0, p1), pkr(p2, p3));       // P: row=n=lc, logical k=j=lg*4+e
            pv[t] = __builtin_amdgcn_mfma_f32_16x16x32_bf16(pa, vf, pv[t], 0, 0, 0);    // att: i=lc, n=lg*4+r
        }
    }

    // ---- denominators via s_l (verified), rescale, att -> s_at ----
#pragma unroll
    for (int t = 0; t < 4; ++t) {
        lp[t] += __shfl_xor(lp[t], 16, 64);
        lp[t] += __shfl_xor(lp[t], 32, 64);
    }
    if (lane < 16) {
#pragma unroll
        for (int t = 0; t < 4; ++t) s_l[wv][t * 16 + lane] = lp[t];
    }
#pragma unroll
    for (int t = 0; t < 4; ++t) {
#pragma unroll
        for (int r = 0; r < 4; ++r) {
            float rl = RCPF(s_l[wv][t * 16 + lg * 4 + r]);
            s_at[(t * 16 + lg * 4 + r) * 72 + wv * 16 + lc] = bf16b(pv[t][r] * rl);
        }
    }

    __syncthreads();   // B3: att complete (fences transposed att writes -> reads)

    // ---- out-proj + direct float4 stores: o = wv*16+lc (C col), n = C row ----
#pragma unroll
    for (int t = 0; t < 4; ++t) {
        floatx4 c = {0.f, 0.f, 0.f, 0.f};
#pragma unroll
        for (int ks = 0; ks < 2; ++ks) {
            short8 a = *(const short8*)&s_at[(t * 16 + lc) * 72 + ks * 32 + lg * 8];
            short8 bfull;
            __builtin_memcpy(&bfull, woutb + (wv * 16 + lc) * 64 + ks * 32 + lg * 8, 16);
            c = __builtin_amdgcn_mfma_f32_16x16x32_bf16(a, bfull, c, 0, 0, 0);
        }
        float* dst = out + ((size_t)b << 23) + (size_t)(wv * 16 + lc) * NPOS
                   + n_base + t * 16 + lg * 4;
        *(floatx4*)dst = c;
    }
}

extern "C" void kernel_launch(void* const* d_in, const int* in_sizes, int n_in,
                              void* d_out, int out_size, void* d_ws, size_t ws_size,
                              hipStream_t stream) {
    const float* x    = (const float*)d_in[0];
    const float* wq   = (const float*)d_in[1];
    const float* wkv  = (const float*)d_in[2];
    const float* wout = (const float*)d_in[3];
    float* out = (float*)d_out;
    float* ws = (float*)d_ws;

    unsigned short* wtb = (unsigned short*)ws;              // [64][128][512] bf16 = 8 MB
    float* partial = ws + 2097152;                          // [32][2][256][128] f32 = 8 MB
    unsigned short* ktu = (unsigned short*)(ws + 4194304);  // [2][4][256][16] bf16
    unsigned short* vtu   = ktu + 32768;                    // [2][4][16][256] bf16
    unsigned short* wqb   = vtu + 32768;                    // [64][64] bf16
    unsigned short* woutb = wqb + 4096;                     // [64][64] bf16

    k_prep_w   <<<16,   256, 0, stream>>>(wq, wout, wqb, woutb);
    k_prep_wkvb<<<4096, 256, 0, stream>>>(wkv, wtb);
    k_conv_mfma<<<256,  256, 0, stream>>>(x, wtb, partial);
    k_reduce   <<<256,  256, 0, stream>>>(partial, ktu, vtu);
    k_attn14   <<<4096, 256, 0, stream>>>(x, wqb, woutb, ktu, vtu, out);
}

// Round 19
// 93.866 us; speedup vs baseline: 1.1497x; 1.1497x over previous
//
#include <hip/hip_runtime.h>
#include <hip/hip_bf16.h>

#define NPOS 131072   // 32*64*64 positions per batch

typedef __attribute__((ext_vector_type(8))) short short8;
typedef __attribute__((ext_vector_type(4))) float floatx4;
typedef unsigned int uint32;

__device__ __forceinline__ unsigned short bf16b(float v) {
    __hip_bfloat16 h = __float2bfloat16(v);
    return __builtin_bit_cast(unsigned short, h);
}
// inline-asm pack: ONLY for values destined to LDS/global (never straight to MFMA)
__device__ __forceinline__ uint32 cvtpk(float lo, float hi) {
    uint32 r;
    asm("v_cvt_pk_bf16_f32 %0, %1, %2" : "=v"(r) : "v"(lo), "v"(hi));
    return r;
}
// cheap rounded pack (round-half-up), compiler-visible; P>0 finite
__device__ __forceinline__ uint32 pkr(float lo, float hi) {
    uint32 ul = __builtin_bit_cast(uint32, lo) + 0x8000u;
    uint32 uh = __builtin_bit_cast(uint32, hi) + 0x8000u;
    return (uh & 0xFFFF0000u) | (ul >> 16);
}
#if __has_builtin(__builtin_amdgcn_exp2f)
#define EXP2(x) __builtin_amdgcn_exp2f(x)
#else
#define EXP2(x) exp2f(x)
#endif
#if __has_builtin(__builtin_amdgcn_rcpf)
#define RCPF(x) __builtin_amdgcn_rcpf(x)
#else
#define RCPF(x) (1.0f / (x))
#endif

// 16x16x32 operand with logical k at slots e=0..3, zeros e=4..7 (proven)
__device__ __forceinline__ short8 emb4(uint32 w0, uint32 w1) {
    union { uint32 u[4]; short8 s; } z;
    z.u[0] = w0; z.u[1] = w1; z.u[2] = 0; z.u[3] = 0;
    return z.s;
}
__device__ __forceinline__ short8 emb4m(const unsigned short* p) {
    uint32 w[2];
    __builtin_memcpy(w, p, 8);
    return emb4(w[0], w[1]);
}
// full 8-slot fragment from 4 packed words
__device__ __forceinline__ short8 mk8(uint32 a, uint32 b, uint32 c, uint32 d) {
    union { uint32 u[4]; short8 s; } z;
    z.u[0] = a; z.u[1] = b; z.u[2] = c; z.u[3] = d;
    return z.s;
}

// ---------------- K0: wq -> bf16*QS, wout -> bf16 ----------------
__global__ void k_prep_w(const float* __restrict__ wq, const float* __restrict__ wout,
                         unsigned short* __restrict__ wqb, unsigned short* __restrict__ woutb) {
    const float QS = 0.36067376022224085f;   // 0.25 * log2(e)
    int gid = blockIdx.x * 256 + threadIdx.x;
    wqb[gid]   = bf16b(wq[gid] * QS);
    woutb[gid] = bf16b(wout[gid]);
}

// ---------------- K1: wkv[oc][ic][term] f32 -> wtb[ic][oc][term] bf16 ----------------
__global__ void k_prep_wkvb(const float* __restrict__ wkv, unsigned short* __restrict__ wtb) {
    int gid = blockIdx.x * 256 + threadIdx.x;
    int ic = gid >> 14;
    int oc = (gid >> 7) & 127;
    float4 v = *(const float4*)(wkv + ((size_t)(oc * 64 + ic)) * 512 + (size_t)(gid & 127) * 4);
    uint32* dst = (uint32*)(wtb + (size_t)gid * 4);
    dst[0] = cvtpk(v.x, v.y);
    dst[1] = cvtpk(v.z, v.w);
}

// ---------------- K2: conv as bf16 MFMA GEMM, split-K over ic (R17-exact, passing) ----------------
__global__ __launch_bounds__(256) void k_conv_mfma(const float* __restrict__ x,
                                                   const unsigned short* __restrict__ wtb,
                                                   float* __restrict__ partial) {
    __shared__ __align__(16) unsigned short As[64 * 72];
    __shared__ __align__(16) unsigned short Bs[128 * 72];
    const int bid = blockIdx.x;
    const int ic = bid & 63;
    const int b  = (bid >> 6) & 1;
    const int pz = bid >> 7;
    const int tid = threadIdx.x;
    const int lane = tid & 63, wv = tid >> 6;
    const int lc = lane & 15, lg = lane >> 4;

    floatx4 acc[4][2];
#pragma unroll
    for (int mt = 0; mt < 4; ++mt)
#pragma unroll
        for (int n = 0; n < 2; ++n) acc[mt][n] = {0.f, 0.f, 0.f, 0.f};

    const float* xp = x + ((size_t)b * 64 + ic) * NPOS + (size_t)pz * 8 * 4096;
    const unsigned short* wp = wtb + (size_t)ic * 128 * 512;

    for (int rz = 0; rz < 8; ++rz) {
        __syncthreads();
        const float* plane = xp + (size_t)rz * 4096;
#pragma unroll
        for (int t2 = 0; t2 < 4; ++t2) {
            int e = (t2 * 256 + tid) * 4;
            int y = e >> 6, x0 = e & 63;
            int p = ((y >> 3) << 3) + (x0 >> 3);
            int k = ((y & 7) << 3) + (x0 & 7);
            float4 v = *(const float4*)(plane + e);
            uint32* dst = (uint32*)&As[p * 72 + k];
            dst[0] = cvtpk(v.x, v.y);
            dst[1] = cvtpk(v.z, v.w);
        }
        {
            int oc = tid >> 1, hf = tid & 1;
            const uint4* src = (const uint4*)(wp + (size_t)oc * 512 + rz * 64 + hf * 32);
            uint4* dst = (uint4*)&Bs[oc * 72 + hf * 32];
#pragma unroll
            for (int r = 0; r < 4; ++r) dst[r] = src[r];
        }
        __syncthreads();
#pragma unroll
        for (int ks = 0; ks < 2; ++ks) {
            short8 bb0 = *(const short8*)&Bs[((wv * 2 + 0) * 16 + lc) * 72 + ks * 32 + lg * 8];
            short8 bb1 = *(const short8*)&Bs[((wv * 2 + 1) * 16 + lc) * 72 + ks * 32 + lg * 8];
#pragma unroll
            for (int mt = 0; mt < 4; ++mt) {
                short8 a = *(const short8*)&As[(mt * 16 + lc) * 72 + ks * 32 + lg * 8];
                acc[mt][0] = __builtin_amdgcn_mfma_f32_16x16x32_bf16(a, bb0, acc[mt][0], 0, 0, 0);
                acc[mt][1] = __builtin_amdgcn_mfma_f32_16x16x32_bf16(a, bb1, acc[mt][1], 0, 0, 0);
            }
        }
    }
    float* pb = partial + (((size_t)ic * 2 + b) * 256 + pz * 64) * 128;
#pragma unroll
    for (int mt = 0; mt < 4; ++mt)
#pragma unroll
        for (int ntl = 0; ntl < 2; ++ntl) {
            int oc = (wv * 2 + ntl) * 16 + lc;
#pragma unroll
            for (int r = 0; r < 4; ++r) {
                int m = mt * 16 + lg * 4 + r;
                pb[(size_t)m * 128 + oc] = acc[mt][ntl][r];
            }
        }
}

// ---------------- K3: reduce over ic; K -> [b][h][256][16]; V -> [b][h][16][256] with
//                  j slot-permuted within each 32-block to match the paired-P fragment ----------------
// P A-frag slot (lg,e): e<4 -> j = 32m + lg*4 + e ; e>=4 -> j = 32m + 16 + lg*4 + (e-4).
// Store V[j] at linear position 32m + lg*8 + e  =>  p = ((q&15)>>2)*8 + (q&3) + ((q>>4)<<2).
__global__ void k_reduce(const float* __restrict__ partial,
                         unsigned short* __restrict__ kt, unsigned short* __restrict__ vt) {
    int gid = blockIdx.x * 256 + threadIdx.x;
    int oc = gid & 127;
    int bp = gid >> 7;          // b*256 + j
    int b = bp >> 8;
    int j = bp & 255;
    const float* p = partial + (size_t)bp * 128 + oc;
    float s = 0.f;
#pragma unroll 8
    for (int ic = 0; ic < 64; ++ic) s += p[(size_t)ic * 65536];
    int h = (oc & 63) >> 4, i = oc & 15;
    if (oc < 64) {
        kt[(((size_t)b * 4 + h) * 256 + j) * 16 + i] = bf16b(s);
    } else {
        int q = j & 31;
        int jp = (j & ~31) | (((q & 15) >> 2) * 8 + (q & 3) + ((q >> 4) << 2));
        vt[(((size_t)b * 4 + h) * 16 + i) * 256 + jp] = bf16b(s);
    }
}

// ---------------- K4: register-P attention; paired full-K PV + ones-MFMA denominators ----------------
// grid 4096 = b(2) x 2048 n-blocks of 64; 256 thr; wave wv = head wv, 64 queries/wave.
__global__ __launch_bounds__(256, 5) void k_attn15(
    const float* __restrict__ x, const unsigned short* __restrict__ wqb,
    const unsigned short* __restrict__ woutb, const unsigned short* __restrict__ kt,
    const unsigned short* __restrict__ vt, float* __restrict__ out)
{
    __shared__ __align__(16) unsigned short s_at[64 * 72];    // x^T then att [n][c]
    __shared__ __align__(16) unsigned short s_q[4][64 * 20];  // per-wave Q [n][i] stride 20

    const int tid = threadIdx.x;
    const int b = blockIdx.x >> 11;
    const int n_base = (blockIdx.x & 2047) << 6;
    const int lane = tid & 63;
    const int wv = tid >> 6;     // head index
    const int lc = lane & 15;
    const int lg = lane >> 4;

    unsigned short* qs = s_q[wv];

    // ---- stage x^T [64][72] cooperatively (verified) ----
    {
        int n_l = tid & 63;
        int c0  = (tid >> 6) * 16;
        const float* xb = x + ((size_t)b << 23) + n_base + n_l;
        uint32* xrow = (uint32*)&s_at[n_l * 72 + c0];
#pragma unroll
        for (int r = 0; r < 8; ++r) {
            float v0 = xb[(size_t)(c0 + 2 * r) << 17];
            float v1 = xb[(size_t)(c0 + 2 * r + 1) << 17];
            xrow[r] = cvtpk(v0, v1);
        }
    }
    __syncthreads();   // B1: x^T staged

    // ---- Q-proj (verified, store stride 20) ----
#pragma unroll
    for (int t = 0; t < 4; ++t) {
        floatx4 c = {0.f, 0.f, 0.f, 0.f};
#pragma unroll
        for (int ks = 0; ks < 2; ++ks) {
            short8 a = *(const short8*)&s_at[(t * 16 + lc) * 72 + ks * 32 + lg * 8];
            short8 bfull;
            __builtin_memcpy(&bfull, wqb + (wv * 16 + lc) * 64 + ks * 32 + lg * 8, 16);
            c = __builtin_amdgcn_mfma_f32_16x16x32_bf16(a, bfull, c, 0, 0, 0);
        }
#pragma unroll
        for (int r = 0; r < 4; ++r)
            qs[(t * 16 + lg * 4 + r) * 20 + lc] = bf16b(c[r]);
    }

    __syncthreads();   // B2: fences transposed Q writes->reads AND Q-proj s_at reads

    // ---- hoist Q B-frags AFTER the barrier: logical k=i=lg*4+e via emb4 ----
    short8 qf[4];
#pragma unroll
    for (int t = 0; t < 4; ++t)
        qf[t] = emb4m(&qs[(t * 16 + lc) * 20 + lg * 4]);

    // ---- head loop: 8 pairs of j-tiles; full-K PV + ones-MFMA denominator ----
    const unsigned short* kh = kt + (((size_t)b * 4 + wv) << 12);
    const unsigned short* vh = vt + (((size_t)b * 4 + wv) << 12);
    const short8 ONES = {(short)0x3F80, (short)0x3F80, (short)0x3F80, (short)0x3F80,
                         (short)0x3F80, (short)0x3F80, (short)0x3F80, (short)0x3F80};
    floatx4 pv[4], pvl[4];
#pragma unroll
    for (int t = 0; t < 4; ++t) { pv[t] = {0.f, 0.f, 0.f, 0.f}; pvl[t] = {0.f, 0.f, 0.f, 0.f}; }

#pragma unroll 2
    for (int m = 0; m < 8; ++m) {
        const int j0 = m * 32;
        short8 kf0 = emb4m(kh + (size_t)(j0 + lc) * 16 + lg * 4);
        short8 kf1 = emb4m(kh + (size_t)(j0 + 16 + lc) * 16 + lg * 4);
        short8 vf;
        __builtin_memcpy(&vf, vh + (size_t)lc * 256 + j0 + lg * 8, 16);  // permuted-j layout
#pragma unroll
        for (int t = 0; t < 4; ++t) {
            floatx4 z = {0.f, 0.f, 0.f, 0.f};
            floatx4 c0 = __builtin_amdgcn_mfma_f32_16x16x32_bf16(kf0, qf[t], z, 0, 0, 0); // j=j0+lg*4+r
            floatx4 c1 = __builtin_amdgcn_mfma_f32_16x16x32_bf16(kf1, qf[t], z, 0, 0, 0); // j=j0+16+lg*4+r
            float p0 = EXP2(c0[0]), p1 = EXP2(c0[1]), p2 = EXP2(c0[2]), p3 = EXP2(c0[3]);
            float p4 = EXP2(c1[0]), p5 = EXP2(c1[1]), p6 = EXP2(c1[2]), p7 = EXP2(c1[3]);
            // pa slots e=0..3 <- even tile r=0..3, e=4..7 <- odd tile r=0..3 (matches vt permutation)
            short8 pa = mk8(pkr(p0, p1), pkr(p2, p3), pkr(p4, p5), pkr(p6, p7));
            pv[t]  = __builtin_amdgcn_mfma_f32_16x16x32_bf16(pa, vf,   pv[t],  0, 0, 0); // att: i=lc, n=lg*4+r
            pvl[t] = __builtin_amdgcn_mfma_f32_16x16x32_bf16(pa, ONES, pvl[t], 0, 0, 0); // l[n] in same slot
        }
    }

    // ---- rescale fully in-lane (denominator already in matching slots), att -> s_at ----
#pragma unroll
    for (int t = 0; t < 4; ++t) {
#pragma unroll
        for (int r = 0; r < 4; ++r) {
            float rl = RCPF(pvl[t][r]);
            s_at[(t * 16 + lg * 4 + r) * 72 + wv * 16 + lc] = bf16b(pv[t][r] * rl);
        }
    }

    __syncthreads();   // B3: att complete (fences transposed att writes -> reads)

    // ---- out-proj + direct float4 stores: o = wv*16+lc (C col), n = C row ----
#pragma unroll
    for (int t = 0; t < 4; ++t) {
        floatx4 c = {0.f, 0.f, 0.f, 0.f};
#pragma unroll
        for (int ks = 0; ks < 2; ++ks) {
            short8 a = *(const short8*)&s_at[(t * 16 + lc) * 72 + ks * 32 + lg * 8];
            short8 bfull;
            __builtin_memcpy(&bfull, woutb + (wv * 16 + lc) * 64 + ks * 32 + lg * 8, 16);
            c = __builtin_amdgcn_mfma_f32_16x16x32_bf16(a, bfull, c, 0, 0, 0);
        }
        float* dst = out + ((size_t)b << 23) + (size_t)(wv * 16 + lc) * NPOS
                   + n_base + t * 16 + lg * 4;
        *(floatx4*)dst = c;
    }
}

extern "C" void kernel_launch(void* const* d_in, const int* in_sizes, int n_in,
                              void* d_out, int out_size, void* d_ws, size_t ws_size,
                              hipStream_t stream) {
    const float* x    = (const float*)d_in[0];
    const float* wq   = (const float*)d_in[1];
    const float* wkv  = (const float*)d_in[2];
    const float* wout = (const float*)d_in[3];
    float* out = (float*)d_out;
    float* ws = (float*)d_ws;

    unsigned short* wtb = (unsigned short*)ws;              // [64][128][512] bf16 = 8 MB
    float* partial = ws + 2097152;                          // [64][2][256][128] f32 = 16 MB
    unsigned short* ktu = (unsigned short*)(ws + 6291456);  // [2][4][256][16] bf16
    unsigned short* vtu   = ktu + 32768;                    // [2][4][16][256] bf16 (j-permuted)
    unsigned short* wqb   = vtu + 32768;                    // [64][64] bf16
    unsigned short* woutb = wqb + 4096;                     // [64][64] bf16

    k_prep_w   <<<16,   256, 0, stream>>>(wq, wout, wqb, woutb);
    k_prep_wkvb<<<4096, 256, 0, stream>>>(wkv, wtb);
    k_conv_mfma<<<512,  256, 0, stream>>>(x, wtb, partial);
    k_reduce   <<<256,  256, 0, stream>>>(partial, ktu, vtu);
    k_attn15   <<<4096, 256, 0, stream>>>(x, wqb, woutb, ktu, vtu, out);
}

// Round 20
// 87.667 us; speedup vs baseline: 1.2310x; 1.0707x over previous
//
#include <hip/hip_runtime.h>
#include <hip/hip_bf16.h>

#define NPOS 131072   // 32*64*64 positions per batch

typedef __attribute__((ext_vector_type(8))) short short8;
typedef __attribute__((ext_vector_type(4))) float floatx4;
typedef unsigned int uint32;

__device__ __forceinline__ unsigned short bf16b(float v) {
    __hip_bfloat16 h = __float2bfloat16(v);
    return __builtin_bit_cast(unsigned short, h);
}
// inline-asm pack: ONLY for values destined to LDS/global (never straight to MFMA)
__device__ __forceinline__ uint32 cvtpk(float lo, float hi) {
    uint32 r;
    asm("v_cvt_pk_bf16_f32 %0, %1, %2" : "=v"(r) : "v"(lo), "v"(hi));
    return r;
}
// cheap rounded pack (round-half-up) via v_perm_b32: 3 VALU ops; P>0 finite
__device__ __forceinline__ uint32 pkr(float lo, float hi) {
    uint32 ul = __builtin_bit_cast(uint32, lo) + 0x8000u;
    uint32 uh = __builtin_bit_cast(uint32, hi) + 0x8000u;
#if __has_builtin(__builtin_amdgcn_perm)
    return __builtin_amdgcn_perm(uh, ul, 0x07060302u);  // [uh.b3,uh.b2,ul.b3,ul.b2]
#else
    return (uh & 0xFFFF0000u) | (ul >> 16);
#endif
}
// cheap scalar round-half-up to bf16 (finite non-NaN inputs)
__device__ __forceinline__ unsigned short bf16r(float v) {
    return (unsigned short)((__builtin_bit_cast(uint32, v) + 0x8000u) >> 16);
}
#if __has_builtin(__builtin_amdgcn_exp2f)
#define EXP2(x) __builtin_amdgcn_exp2f(x)
#else
#define EXP2(x) exp2f(x)
#endif
#if __has_builtin(__builtin_amdgcn_rcpf)
#define RCPF(x) __builtin_amdgcn_rcpf(x)
#else
#define RCPF(x) (1.0f / (x))
#endif

// 16x16x32 operand with logical k at slots e=0..3, zeros e=4..7 (proven)
__device__ __forceinline__ short8 emb4(uint32 w0, uint32 w1) {
    union { uint32 u[4]; short8 s; } z;
    z.u[0] = w0; z.u[1] = w1; z.u[2] = 0; z.u[3] = 0;
    return z.s;
}
__device__ __forceinline__ short8 emb4m(const unsigned short* p) {
    uint32 w[2];
    __builtin_memcpy(w, p, 8);
    return emb4(w[0], w[1]);
}
__device__ __forceinline__ short8 mk8(uint32 a, uint32 b, uint32 c, uint32 d) {
    union { uint32 u[4]; short8 s; } z;
    z.u[0] = a; z.u[1] = b; z.u[2] = c; z.u[3] = d;
    return z.s;
}

// ---------------- K0: wq -> bf16*QS, wout -> bf16 ----------------
__global__ void k_prep_w(const float* __restrict__ wq, const float* __restrict__ wout,
                         unsigned short* __restrict__ wqb, unsigned short* __restrict__ woutb) {
    const float QS = 0.36067376022224085f;   // 0.25 * log2(e)
    int gid = blockIdx.x * 256 + threadIdx.x;
    wqb[gid]   = bf16b(wq[gid] * QS);
    woutb[gid] = bf16b(wout[gid]);
}

// ---------------- K1: wkv[oc][ic][term] f32 -> wtb[ic][oc][term] bf16 ----------------
__global__ void k_prep_wkvb(const float* __restrict__ wkv, unsigned short* __restrict__ wtb) {
    int gid = blockIdx.x * 256 + threadIdx.x;
    int ic = gid >> 14;
    int oc = (gid >> 7) & 127;
    float4 v = *(const float4*)(wkv + ((size_t)(oc * 64 + ic)) * 512 + (size_t)(gid & 127) * 4);
    uint32* dst = (uint32*)(wtb + (size_t)gid * 4);
    dst[0] = cvtpk(v.x, v.y);
    dst[1] = cvtpk(v.z, v.w);
}

// ---------------- K2: conv as bf16 MFMA GEMM, split-K over ic (R17/R19-exact) ----------------
__global__ __launch_bounds__(256) void k_conv_mfma(const float* __restrict__ x,
                                                   const unsigned short* __restrict__ wtb,
                                                   float* __restrict__ partial) {
    __shared__ __align__(16) unsigned short As[64 * 72];
    __shared__ __align__(16) unsigned short Bs[128 * 72];
    const int bid = blockIdx.x;
    const int ic = bid & 63;
    const int b  = (bid >> 6) & 1;
    const int pz = bid >> 7;
    const int tid = threadIdx.x;
    const int lane = tid & 63, wv = tid >> 6;
    const int lc = lane & 15, lg = lane >> 4;

    floatx4 acc[4][2];
#pragma unroll
    for (int mt = 0; mt < 4; ++mt)
#pragma unroll
        for (int n = 0; n < 2; ++n) acc[mt][n] = {0.f, 0.f, 0.f, 0.f};

    const float* xp = x + ((size_t)b * 64 + ic) * NPOS + (size_t)pz * 8 * 4096;
    const unsigned short* wp = wtb + (size_t)ic * 128 * 512;

    for (int rz = 0; rz < 8; ++rz) {
        __syncthreads();
        const float* plane = xp + (size_t)rz * 4096;
#pragma unroll
        for (int t2 = 0; t2 < 4; ++t2) {
            int e = (t2 * 256 + tid) * 4;
            int y = e >> 6, x0 = e & 63;
            int p = ((y >> 3) << 3) + (x0 >> 3);
            int k = ((y & 7) << 3) + (x0 & 7);
            float4 v = *(const float4*)(plane + e);
            uint32* dst = (uint32*)&As[p * 72 + k];
            dst[0] = cvtpk(v.x, v.y);
            dst[1] = cvtpk(v.z, v.w);
        }
        {
            int oc = tid >> 1, hf = tid & 1;
            const uint4* src = (const uint4*)(wp + (size_t)oc * 512 + rz * 64 + hf * 32);
            uint4* dst = (uint4*)&Bs[oc * 72 + hf * 32];
#pragma unroll
            for (int r = 0; r < 4; ++r) dst[r] = src[r];
        }
        __syncthreads();
#pragma unroll
        for (int ks = 0; ks < 2; ++ks) {
            short8 bb0 = *(const short8*)&Bs[((wv * 2 + 0) * 16 + lc) * 72 + ks * 32 + lg * 8];
            short8 bb1 = *(const short8*)&Bs[((wv * 2 + 1) * 16 + lc) * 72 + ks * 32 + lg * 8];
#pragma unroll
            for (int mt = 0; mt < 4; ++mt) {
                short8 a = *(const short8*)&As[(mt * 16 + lc) * 72 + ks * 32 + lg * 8];
                acc[mt][0] = __builtin_amdgcn_mfma_f32_16x16x32_bf16(a, bb0, acc[mt][0], 0, 0, 0);
                acc[mt][1] = __builtin_amdgcn_mfma_f32_16x16x32_bf16(a, bb1, acc[mt][1], 0, 0, 0);
            }
        }
    }
    float* pb = partial + (((size_t)ic * 2 + b) * 256 + pz * 64) * 128;
#pragma unroll
    for (int mt = 0; mt < 4; ++mt)
#pragma unroll
        for (int ntl = 0; ntl < 2; ++ntl) {
            int oc = (wv * 2 + ntl) * 16 + lc;
#pragma unroll
            for (int r = 0; r < 4; ++r) {
                int m = mt * 16 + lg * 4 + r;
                pb[(size_t)m * 128 + oc] = acc[mt][ntl][r];
            }
        }
}

// ---------------- K3: reduce over ic; K -> [b][h][256][16]; V j-permuted (R19-exact) ----------------
__global__ void k_reduce(const float* __restrict__ partial,
                         unsigned short* __restrict__ kt, unsigned short* __restrict__ vt) {
    int gid = blockIdx.x * 256 + threadIdx.x;
    int oc = gid & 127;
    int bp = gid >> 7;          // b*256 + j
    int b = bp >> 8;
    int j = bp & 255;
    const float* p = partial + (size_t)bp * 128 + oc;
    float s = 0.f;
#pragma unroll 8
    for (int ic = 0; ic < 64; ++ic) s += p[(size_t)ic * 65536];
    int h = (oc & 63) >> 4, i = oc & 15;
    if (oc < 64) {
        kt[(((size_t)b * 4 + h) * 256 + j) * 16 + i] = bf16b(s);
    } else {
        int q = j & 31;
        int jp = (j & ~31) | (((q & 15) >> 2) * 8 + (q & 3) + ((q >> 4) << 2));
        vt[(((size_t)b * 4 + h) * 16 + i) * 256 + jp] = bf16b(s);
    }
}

// ---------------- K4: R19 attn + VALU micro-opts (perm-pkr, cheap att round, addr hygiene) ----------------
// grid 4096 = b(2) x 2048 n-blocks of 64; 256 thr; wave wv = head wv, 64 queries/wave.
__global__ __launch_bounds__(256, 5) void k_attn16(
    const float* __restrict__ x, const unsigned short* __restrict__ wqb,
    const unsigned short* __restrict__ woutb, const unsigned short* __restrict__ kt,
    const unsigned short* __restrict__ vt, float* __restrict__ out)
{
    __shared__ __align__(16) unsigned short s_at[64 * 72];    // x^T then att [n][c]
    __shared__ __align__(16) unsigned short s_q[4][64 * 20];  // per-wave Q [n][i] stride 20

    const int tid = threadIdx.x;
    const int b = blockIdx.x >> 11;
    const int n_base = (blockIdx.x & 2047) << 6;
    const int lane = tid & 63;
    const int wv = tid >> 6;     // head index
    const int lc = lane & 15;
    const int lg = lane >> 4;

    unsigned short* qs = s_q[wv];

    // ---- stage x^T [64][72] cooperatively (verified) ----
    {
        int n_l = tid & 63;
        int c0  = (tid >> 6) * 16;
        const float* xb = x + ((size_t)b << 23) + n_base + n_l;
        uint32* xrow = (uint32*)&s_at[n_l * 72 + c0];
#pragma unroll
        for (int r = 0; r < 8; ++r) {
            float v0 = xb[(size_t)(c0 + 2 * r) << 17];
            float v1 = xb[(size_t)(c0 + 2 * r + 1) << 17];
            xrow[r] = cvtpk(v0, v1);
        }
    }
    __syncthreads();   // B1: x^T staged

    // ---- Q-proj (verified, store stride 20) ----
#pragma unroll
    for (int t = 0; t < 4; ++t) {
        floatx4 c = {0.f, 0.f, 0.f, 0.f};
#pragma unroll
        for (int ks = 0; ks < 2; ++ks) {
            short8 a = *(const short8*)&s_at[(t * 16 + lc) * 72 + ks * 32 + lg * 8];
            short8 bfull;
            __builtin_memcpy(&bfull, wqb + (wv * 16 + lc) * 64 + ks * 32 + lg * 8, 16);
            c = __builtin_amdgcn_mfma_f32_16x16x32_bf16(a, bfull, c, 0, 0, 0);
        }
#pragma unroll
        for (int r = 0; r < 4; ++r)
            qs[(t * 16 + lg * 4 + r) * 20 + lc] = bf16b(c[r]);
    }

    __syncthreads();   // B2: fences transposed Q writes->reads AND Q-proj s_at reads

    // ---- hoist Q B-frags AFTER the barrier: logical k=i=lg*4+e via emb4 ----
    short8 qf[4];
#pragma unroll
    for (int t = 0; t < 4; ++t)
        qf[t] = emb4m(&qs[(t * 16 + lc) * 20 + lg * 4]);

    // ---- head loop: 8 pairs of j-tiles; full-K PV + ones-MFMA denominator ----
    // loop-invariant base pointers (unrolled loads become base+immediate)
    const unsigned short* kbase = kt + (((size_t)b * 4 + wv) << 12) + lc * 16 + lg * 4;
    const unsigned short* vbase = vt + (((size_t)b * 4 + wv) << 12) + lc * 256 + lg * 8;
    const short8 ONES = {(short)0x3F80, (short)0x3F80, (short)0x3F80, (short)0x3F80,
                         (short)0x3F80, (short)0x3F80, (short)0x3F80, (short)0x3F80};
    const floatx4 Z = {0.f, 0.f, 0.f, 0.f};
    floatx4 pv[4], pvl[4];
#pragma unroll
    for (int t = 0; t < 4; ++t) { pv[t] = Z; pvl[t] = Z; }

#pragma unroll
    for (int m = 0; m < 8; ++m) {
        short8 kf0 = emb4m(kbase + m * 512);          // j = m*32 + lc rows
        short8 kf1 = emb4m(kbase + m * 512 + 256);    // j = m*32 + 16 + lc rows
        short8 vf;
        __builtin_memcpy(&vf, vbase + m * 32, 16);    // permuted-j layout
#pragma unroll
        for (int t = 0; t < 4; ++t) {
            floatx4 c0 = __builtin_amdgcn_mfma_f32_16x16x32_bf16(kf0, qf[t], Z, 0, 0, 0); // j=j0+lg*4+r
            floatx4 c1 = __builtin_amdgcn_mfma_f32_16x16x32_bf16(kf1, qf[t], Z, 0, 0, 0); // j=j0+16+lg*4+r
            float p0 = EXP2(c0[0]), p1 = EXP2(c0[1]), p2 = EXP2(c0[2]), p3 = EXP2(c0[3]);
            float p4 = EXP2(c1[0]), p5 = EXP2(c1[1]), p6 = EXP2(c1[2]), p7 = EXP2(c1[3]);
            short8 pa = mk8(pkr(p0, p1), pkr(p2, p3), pkr(p4, p5), pkr(p6, p7));
            pv[t]  = __builtin_amdgcn_mfma_f32_16x16x32_bf16(pa, vf,   pv[t],  0, 0, 0); // att: i=lc, n=lg*4+r
            pvl[t] = __builtin_amdgcn_mfma_f32_16x16x32_bf16(pa, ONES, pvl[t], 0, 0, 0); // l[n] same slot
        }
    }

    // ---- rescale in-lane; cheap-round att -> s_at ----
#pragma unroll
    for (int t = 0; t < 4; ++t) {
#pragma unroll
        for (int r = 0; r < 4; ++r) {
            float rl = RCPF(pvl[t][r]);
            s_at[(t * 16 + lg * 4 + r) * 72 + wv * 16 + lc] = bf16r(pv[t][r] * rl);
        }
    }

    __syncthreads();   // B3: att complete (fences transposed att writes -> reads)

    // ---- out-proj + direct float4 stores: o = wv*16+lc (C col), n = C row ----
#pragma unroll
    for (int t = 0; t < 4; ++t) {
        floatx4 c = {0.f, 0.f, 0.f, 0.f};
#pragma unroll
        for (int ks = 0; ks < 2; ++ks) {
            short8 a = *(const short8*)&s_at[(t * 16 + lc) * 72 + ks * 32 + lg * 8];
            short8 bfull;
            __builtin_memcpy(&bfull, woutb + (wv * 16 + lc) * 64 + ks * 32 + lg * 8, 16);
            c = __builtin_amdgcn_mfma_f32_16x16x32_bf16(a, bfull, c, 0, 0, 0);
        }
        float* dst = out + ((size_t)b << 23) + (size_t)(wv * 16 + lc) * NPOS
                   + n_base + t * 16 + lg * 4;
        *(floatx4*)dst = c;
    }
}

extern "C" void kernel_launch(void* const* d_in, const int* in_sizes, int n_in,
                              void* d_out, int out_size, void* d_ws, size_t ws_size,
                              hipStream_t stream) {
    const float* x    = (const float*)d_in[0];
    const float* wq   = (const float*)d_in[1];
    const float* wkv  = (const float*)d_in[2];
    const float* wout = (const float*)d_in[3];
    float* out = (float*)d_out;
    float* ws = (float*)d_ws;

    unsigned short* wtb = (unsigned short*)ws;              // [64][128][512] bf16 = 8 MB
    float* partial = ws + 2097152;                          // [64][2][256][128] f32 = 16 MB
    unsigned short* ktu = (unsigned short*)(ws + 6291456);  // [2][4][256][16] bf16
    unsigned short* vtu   = ktu + 32768;                    // [2][4][16][256] bf16 (j-permuted)
    unsigned short* wqb   = vtu + 32768;                    // [64][64] bf16
    unsigned short* woutb = wqb + 4096;                     // [64][64] bf16

    k_prep_w   <<<16,   256, 0, stream>>>(wq, wout, wqb, woutb);
    k_prep_wkvb<<<4096, 256, 0, stream>>>(wkv, wtb);
    k_conv_mfma<<<512,  256, 0, stream>>>(x, wtb, partial);
    k_reduce   <<<256,  256, 0, stream>>>(partial, ktu, vtu);
    k_attn16   <<<4096, 256, 0, stream>>>(x, wqb, woutb, ktu, vtu, out);
}

// Round 21
// 87.468 us; speedup vs baseline: 1.2338x; 1.0023x over previous
//
#include <hip/hip_runtime.h>
#include <hip/hip_bf16.h>

#define NPOS 131072   // 32*64*64 positions per batch

typedef __attribute__((ext_vector_type(8))) short short8;
typedef __attribute__((ext_vector_type(4))) float floatx4;
typedef unsigned int uint32;

__device__ __forceinline__ unsigned short bf16b(float v) {
    __hip_bfloat16 h = __float2bfloat16(v);
    return __builtin_bit_cast(unsigned short, h);
}
// inline-asm pack: ONLY for values destined to LDS/global (never straight to MFMA)
__device__ __forceinline__ uint32 cvtpk(float lo, float hi) {
    uint32 r;
    asm("v_cvt_pk_bf16_f32 %0, %1, %2" : "=v"(r) : "v"(lo), "v"(hi));
    return r;
}
// cheap rounded pack (round-half-up) via v_perm_b32: 3 VALU ops; P>0 finite
__device__ __forceinline__ uint32 pkr(float lo, float hi) {
    uint32 ul = __builtin_bit_cast(uint32, lo) + 0x8000u;
    uint32 uh = __builtin_bit_cast(uint32, hi) + 0x8000u;
#if __has_builtin(__builtin_amdgcn_perm)
    return __builtin_amdgcn_perm(uh, ul, 0x07060302u);  // [uh.b3,uh.b2,ul.b3,ul.b2]
#else
    return (uh & 0xFFFF0000u) | (ul >> 16);
#endif
}
// cheap scalar round-half-up to bf16 (finite non-NaN inputs)
__device__ __forceinline__ unsigned short bf16r(float v) {
    return (unsigned short)((__builtin_bit_cast(uint32, v) + 0x8000u) >> 16);
}
#if __has_builtin(__builtin_amdgcn_exp2f)
#define EXP2(x) __builtin_amdgcn_exp2f(x)
#else
#define EXP2(x) exp2f(x)
#endif
#if __has_builtin(__builtin_amdgcn_rcpf)
#define RCPF(x) __builtin_amdgcn_rcpf(x)
#else
#define RCPF(x) (1.0f / (x))
#endif

// 16x16x32 operand with logical k at slots e=0..3, zeros e=4..7 (proven)
__device__ __forceinline__ short8 emb4(uint32 w0, uint32 w1) {
    union { uint32 u[4]; short8 s; } z;
    z.u[0] = w0; z.u[1] = w1; z.u[2] = 0; z.u[3] = 0;
    return z.s;
}
__device__ __forceinline__ short8 emb4m(const unsigned short* p) {
    uint32 w[2];
    __builtin_memcpy(w, p, 8);
    return emb4(w[0], w[1]);
}
__device__ __forceinline__ short8 mk8(uint32 a, uint32 b, uint32 c, uint32 d) {
    union { uint32 u[4]; short8 s; } z;
    z.u[0] = a; z.u[1] = b; z.u[2] = c; z.u[3] = d;
    return z.s;
}

// ---------------- K2: conv as bf16 MFMA GEMM; B staged DIRECTLY from wkv f32 ----------------
// grid 512: ic = bid&63 (XCD-affine: blocks sharing ic land on one XCD -> L2 reuse),
// b = (bid>>6)&1, pz = bid>>7; 256 thr (4 waves). Same math as the verified conv.
__global__ __launch_bounds__(256) void k_conv_mfma(const float* __restrict__ x,
                                                   const float* __restrict__ wkv,
                                                   float* __restrict__ partial) {
    __shared__ __align__(16) unsigned short As[64 * 72];
    __shared__ __align__(16) unsigned short Bs[128 * 72];
    const int bid = blockIdx.x;
    const int ic = bid & 63;
    const int b  = (bid >> 6) & 1;
    const int pz = bid >> 7;
    const int tid = threadIdx.x;
    const int lane = tid & 63, wv = tid >> 6;
    const int lc = lane & 15, lg = lane >> 4;

    floatx4 acc[4][2];
#pragma unroll
    for (int mt = 0; mt < 4; ++mt)
#pragma unroll
        for (int n = 0; n < 2; ++n) acc[mt][n] = {0.f, 0.f, 0.f, 0.f};

    const float* xp = x + ((size_t)b * 64 + ic) * NPOS + (size_t)pz * 8 * 4096;
    const int oc = tid >> 1, hf = tid & 1;
    const float* wsrc = wkv + ((size_t)(oc * 64 + ic)) * 512 + hf * 32;

    for (int rz = 0; rz < 8; ++rz) {
        __syncthreads();
        // stage A: one z-plane -> patch-major bf16 (verified)
        const float* plane = xp + (size_t)rz * 4096;
#pragma unroll
        for (int t2 = 0; t2 < 4; ++t2) {
            int e = (t2 * 256 + tid) * 4;
            int y = e >> 6, x0 = e & 63;
            int p = ((y >> 3) << 3) + (x0 >> 3);
            int k = ((y & 7) << 3) + (x0 & 7);
            float4 v = *(const float4*)(plane + e);
            uint32* dst = (uint32*)&As[p * 72 + k];
            dst[0] = cvtpk(v.x, v.y);
            dst[1] = cvtpk(v.z, v.w);
        }
        // stage B: wkv[oc][ic][rz*64 + hf*32 .. +32] f32 -> bf16 (bit-identical to old prep)
        {
            const float4* s4 = (const float4*)(wsrc + rz * 64);
            uint32* d = (uint32*)&Bs[oc * 72 + hf * 32];
#pragma unroll
            for (int r = 0; r < 8; ++r) {
                float4 v = s4[r];
                d[2 * r]     = cvtpk(v.x, v.y);
                d[2 * r + 1] = cvtpk(v.z, v.w);
            }
        }
        __syncthreads();
#pragma unroll
        for (int ks = 0; ks < 2; ++ks) {
            short8 bb0 = *(const short8*)&Bs[((wv * 2 + 0) * 16 + lc) * 72 + ks * 32 + lg * 8];
            short8 bb1 = *(const short8*)&Bs[((wv * 2 + 1) * 16 + lc) * 72 + ks * 32 + lg * 8];
#pragma unroll
            for (int mt = 0; mt < 4; ++mt) {
                short8 a = *(const short8*)&As[(mt * 16 + lc) * 72 + ks * 32 + lg * 8];
                acc[mt][0] = __builtin_amdgcn_mfma_f32_16x16x32_bf16(a, bb0, acc[mt][0], 0, 0, 0);
                acc[mt][1] = __builtin_amdgcn_mfma_f32_16x16x32_bf16(a, bb1, acc[mt][1], 0, 0, 0);
            }
        }
    }
    float* pb = partial + (((size_t)ic * 2 + b) * 256 + pz * 64) * 128;
#pragma unroll
    for (int mt = 0; mt < 4; ++mt)
#pragma unroll
        for (int ntl = 0; ntl < 2; ++ntl) {
            int oco = (wv * 2 + ntl) * 16 + lc;
#pragma unroll
            for (int r = 0; r < 4; ++r) {
                int m = mt * 16 + lg * 4 + r;
                pb[(size_t)m * 128 + oco] = acc[mt][ntl][r];
            }
        }
}

// ---------------- K3: reduce over ic (+ folded weight prep); K -> [b][h][256][16];
//                  V j-permuted [b][h][16][256] (R19/R20-exact mapping) ----------------
__global__ void k_reduce(const float* __restrict__ partial,
                         const float* __restrict__ wq, const float* __restrict__ wout,
                         unsigned short* __restrict__ kt, unsigned short* __restrict__ vt,
                         unsigned short* __restrict__ wqb, unsigned short* __restrict__ woutb) {
    int gid = blockIdx.x * 256 + threadIdx.x;
    if (gid < 4096) {
        const float QS = 0.36067376022224085f;   // 0.25 * log2(e)
        wqb[gid]   = bf16b(wq[gid] * QS);
        woutb[gid] = bf16b(wout[gid]);
    }
    int oc = gid & 127;
    int bp = gid >> 7;          // b*256 + j
    int b = bp >> 8;
    int j = bp & 255;
    const float* p = partial + (size_t)bp * 128 + oc;
    float s = 0.f;
#pragma unroll 8
    for (int ic = 0; ic < 64; ++ic) s += p[(size_t)ic * 65536];
    int h = (oc & 63) >> 4, i = oc & 15;
    if (oc < 64) {
        kt[(((size_t)b * 4 + h) * 256 + j) * 16 + i] = bf16b(s);
    } else {
        int q = j & 31;
        int jp = (j & ~31) | (((q & 15) >> 2) * 8 + (q & 3) + ((q >> 4) << 2));
        vt[(((size_t)b * 4 + h) * 16 + i) * 256 + jp] = bf16b(s);
    }
}

// ---------------- K4: R20-exact attention (unchanged, passing) ----------------
__global__ __launch_bounds__(256, 5) void k_attn16(
    const float* __restrict__ x, const unsigned short* __restrict__ wqb,
    const unsigned short* __restrict__ woutb, const unsigned short* __restrict__ kt,
    const unsigned short* __restrict__ vt, float* __restrict__ out)
{
    __shared__ __align__(16) unsigned short s_at[64 * 72];    // x^T then att [n][c]
    __shared__ __align__(16) unsigned short s_q[4][64 * 20];  // per-wave Q [n][i] stride 20

    const int tid = threadIdx.x;
    const int b = blockIdx.x >> 11;
    const int n_base = (blockIdx.x & 2047) << 6;
    const int lane = tid & 63;
    const int wv = tid >> 6;     // head index
    const int lc = lane & 15;
    const int lg = lane >> 4;

    unsigned short* qs = s_q[wv];

    // ---- stage x^T [64][72] cooperatively (verified) ----
    {
        int n_l = tid & 63;
        int c0  = (tid >> 6) * 16;
        const float* xb = x + ((size_t)b << 23) + n_base + n_l;
        uint32* xrow = (uint32*)&s_at[n_l * 72 + c0];
#pragma unroll
        for (int r = 0; r < 8; ++r) {
            float v0 = xb[(size_t)(c0 + 2 * r) << 17];
            float v1 = xb[(size_t)(c0 + 2 * r + 1) << 17];
            xrow[r] = cvtpk(v0, v1);
        }
    }
    __syncthreads();   // B1: x^T staged

    // ---- Q-proj (verified, store stride 20) ----
#pragma unroll
    for (int t = 0; t < 4; ++t) {
        floatx4 c = {0.f, 0.f, 0.f, 0.f};
#pragma unroll
        for (int ks = 0; ks < 2; ++ks) {
            short8 a = *(const short8*)&s_at[(t * 16 + lc) * 72 + ks * 32 + lg * 8];
            short8 bfull;
            __builtin_memcpy(&bfull, wqb + (wv * 16 + lc) * 64 + ks * 32 + lg * 8, 16);
            c = __builtin_amdgcn_mfma_f32_16x16x32_bf16(a, bfull, c, 0, 0, 0);
        }
#pragma unroll
        for (int r = 0; r < 4; ++r)
            qs[(t * 16 + lg * 4 + r) * 20 + lc] = bf16b(c[r]);
    }

    __syncthreads();   // B2: fences transposed Q writes->reads AND Q-proj s_at reads

    // ---- hoist Q B-frags AFTER the barrier: logical k=i=lg*4+e via emb4 ----
    short8 qf[4];
#pragma unroll
    for (int t = 0; t < 4; ++t)
        qf[t] = emb4m(&qs[(t * 16 + lc) * 20 + lg * 4]);

    // ---- head loop: 8 pairs of j-tiles; full-K PV + ones-MFMA denominator ----
    const unsigned short* kbase = kt + (((size_t)b * 4 + wv) << 12) + lc * 16 + lg * 4;
    const unsigned short* vbase = vt + (((size_t)b * 4 + wv) << 12) + lc * 256 + lg * 8;
    const short8 ONES = {(short)0x3F80, (short)0x3F80, (short)0x3F80, (short)0x3F80,
                         (short)0x3F80, (short)0x3F80, (short)0x3F80, (short)0x3F80};
    const floatx4 Z = {0.f, 0.f, 0.f, 0.f};
    floatx4 pv[4], pvl[4];
#pragma unroll
    for (int t = 0; t < 4; ++t) { pv[t] = Z; pvl[t] = Z; }

#pragma unroll
    for (int m = 0; m < 8; ++m) {
        short8 kf0 = emb4m(kbase + m * 512);          // j = m*32 + lc rows
        short8 kf1 = emb4m(kbase + m * 512 + 256);    // j = m*32 + 16 + lc rows
        short8 vf;
        __builtin_memcpy(&vf, vbase + m * 32, 16);    // permuted-j layout
#pragma unroll
        for (int t = 0; t < 4; ++t) {
            floatx4 c0 = __builtin_amdgcn_mfma_f32_16x16x32_bf16(kf0, qf[t], Z, 0, 0, 0); // j=j0+lg*4+r
            floatx4 c1 = __builtin_amdgcn_mfma_f32_16x16x32_bf16(kf1, qf[t], Z, 0, 0, 0); // j=j0+16+lg*4+r
            float p0 = EXP2(c0[0]), p1 = EXP2(c0[1]), p2 = EXP2(c0[2]), p3 = EXP2(c0[3]);
            float p4 = EXP2(c1[0]), p5 = EXP2(c1[1]), p6 = EXP2(c1[2]), p7 = EXP2(c1[3]);
            short8 pa = mk8(pkr(p0, p1), pkr(p2, p3), pkr(p4, p5), pkr(p6, p7));
            pv[t]  = __builtin_amdgcn_mfma_f32_16x16x32_bf16(pa, vf,   pv[t],  0, 0, 0); // att: i=lc, n=lg*4+r
            pvl[t] = __builtin_amdgcn_mfma_f32_16x16x32_bf16(pa, ONES, pvl[t], 0, 0, 0); // l[n] same slot
        }
    }

    // ---- rescale in-lane; cheap-round att -> s_at ----
#pragma unroll
    for (int t = 0; t < 4; ++t) {
#pragma unroll
        for (int r = 0; r < 4; ++r) {
            float rl = RCPF(pvl[t][r]);
            s_at[(t * 16 + lg * 4 + r) * 72 + wv * 16 + lc] = bf16r(pv[t][r] * rl);
        }
    }

    __syncthreads();   // B3: att complete (fences transposed att writes -> reads)

    // ---- out-proj + direct float4 stores: o = wv*16+lc (C col), n = C row ----
#pragma unroll
    for (int t = 0; t < 4; ++t) {
        floatx4 c = {0.f, 0.f, 0.f, 0.f};
#pragma unroll
        for (int ks = 0; ks < 2; ++ks) {
            short8 a = *(const short8*)&s_at[(t * 16 + lc) * 72 + ks * 32 + lg * 8];
            short8 bfull;
            __builtin_memcpy(&bfull, woutb + (wv * 16 + lc) * 64 + ks * 32 + lg * 8, 16);
            c = __builtin_amdgcn_mfma_f32_16x16x32_bf16(a, bfull, c, 0, 0, 0);
        }
        float* dst = out + ((size_t)b << 23) + (size_t)(wv * 16 + lc) * NPOS
                   + n_base + t * 16 + lg * 4;
        *(floatx4*)dst = c;
    }
}

extern "C" void kernel_launch(void* const* d_in, const int* in_sizes, int n_in,
                              void* d_out, int out_size, void* d_ws, size_t ws_size,
                              hipStream_t stream) {
    const float* x    = (const float*)d_in[0];
    const float* wq   = (const float*)d_in[1];
    const float* wkv  = (const float*)d_in[2];
    const float* wout = (const float*)d_in[3];
    float* out = (float*)d_out;
    float* ws = (float*)d_ws;

    float* partial = ws;                                    // [64][2][256][128] f32 = 16 MB
    unsigned short* ktu   = (unsigned short*)(ws + 4194304);  // [2][4][256][16] bf16
    unsigned short* vtu   = ktu + 32768;                    // [2][4][16][256] bf16 (j-permuted)
    unsigned short* wqb   = vtu + 32768;                    // [64][64] bf16
    unsigned short* woutb = wqb + 4096;                     // [64][64] bf16

    k_conv_mfma<<<512,  256, 0, stream>>>(x, wkv, partial);
    k_reduce   <<<256,  256, 0, stream>>>(partial, wq, wout, ktu, vtu, wqb, woutb);
    k_attn16   <<<4096, 256, 0, stream>>>(x, wqb, woutb, ktu, vtu, out);
}

// Round 22
// 82.124 us; speedup vs baseline: 1.3141x; 1.0651x over previous
//
#include <hip/hip_runtime.h>
#include <hip/hip_bf16.h>

#define NPOS 131072   // 32*64*64 positions per batch

typedef __attribute__((ext_vector_type(8))) short short8;
typedef __attribute__((ext_vector_type(4))) float floatx4;
typedef unsigned int uint32;

__device__ __forceinline__ unsigned short bf16b(float v) {
    __hip_bfloat16 h = __float2bfloat16(v);
    return __builtin_bit_cast(unsigned short, h);
}
// inline-asm pack: ONLY for values destined to LDS/global (never straight to MFMA)
__device__ __forceinline__ uint32 cvtpk(float lo, float hi) {
    uint32 r;
    asm("v_cvt_pk_bf16_f32 %0, %1, %2" : "=v"(r) : "v"(lo), "v"(hi));
    return r;
}
// TRUNCATING pack via one v_perm_b32 (P>0 finite; same P feeds numerator AND
// denominator MFMAs so the quantization largely cancels in the ratio)
__device__ __forceinline__ uint32 pkt(float lo, float hi) {
    uint32 ul = __builtin_bit_cast(uint32, lo);
    uint32 uh = __builtin_bit_cast(uint32, hi);
#if __has_builtin(__builtin_amdgcn_perm)
    return __builtin_amdgcn_perm(uh, ul, 0x07060302u);  // [uh.b3,uh.b2,ul.b3,ul.b2]
#else
    return (uh & 0xFFFF0000u) | (ul >> 16);
#endif
}
// cheap scalar round-half-up to bf16 (finite non-NaN inputs)
__device__ __forceinline__ unsigned short bf16r(float v) {
    return (unsigned short)((__builtin_bit_cast(uint32, v) + 0x8000u) >> 16);
}
#if __has_builtin(__builtin_amdgcn_exp2f)
#define EXP2(x) __builtin_amdgcn_exp2f(x)
#else
#define EXP2(x) exp2f(x)
#endif
#if __has_builtin(__builtin_amdgcn_rcpf)
#define RCPF(x) __builtin_amdgcn_rcpf(x)
#else
#define RCPF(x) (1.0f / (x))
#endif

// 16x16x32 operand with logical k at slots e=0..3, zeros e=4..7 (proven)
__device__ __forceinline__ short8 emb4(uint32 w0, uint32 w1) {
    union { uint32 u[4]; short8 s; } z;
    z.u[0] = w0; z.u[1] = w1; z.u[2] = 0; z.u[3] = 0;
    return z.s;
}
__device__ __forceinline__ short8 emb4m(const unsigned short* p) {
    uint32 w[2];
    __builtin_memcpy(w, p, 8);
    return emb4(w[0], w[1]);
}
__device__ __forceinline__ short8 mk8(uint32 a, uint32 b, uint32 c, uint32 d) {
    union { uint32 u[4]; short8 s; } z;
    z.u[0] = a; z.u[1] = b; z.u[2] = c; z.u[3] = d;
    return z.s;
}

// ---------------- K2: conv as bf16 MFMA GEMM; B staged from wkv f32; bf16 partial ----------------
// grid 512: ic = bid&63 (XCD-affine), b = (bid>>6)&1, pz = bid>>7; 256 thr (4 waves)
__global__ __launch_bounds__(256) void k_conv_mfma(const float* __restrict__ x,
                                                   const float* __restrict__ wkv,
                                                   unsigned short* __restrict__ partial) {
    __shared__ __align__(16) unsigned short As[64 * 72];
    __shared__ __align__(16) unsigned short Bs[128 * 72];
    const int bid = blockIdx.x;
    const int ic = bid & 63;
    const int b  = (bid >> 6) & 1;
    const int pz = bid >> 7;
    const int tid = threadIdx.x;
    const int lane = tid & 63, wv = tid >> 6;
    const int lc = lane & 15, lg = lane >> 4;

    floatx4 acc[4][2];
#pragma unroll
    for (int mt = 0; mt < 4; ++mt)
#pragma unroll
        for (int n = 0; n < 2; ++n) acc[mt][n] = {0.f, 0.f, 0.f, 0.f};

    const float* xp = x + ((size_t)b * 64 + ic) * NPOS + (size_t)pz * 8 * 4096;
    const int oc = tid >> 1, hf = tid & 1;
    const float* wsrc = wkv + ((size_t)(oc * 64 + ic)) * 512 + hf * 32;

    for (int rz = 0; rz < 8; ++rz) {
        __syncthreads();
        const float* plane = xp + (size_t)rz * 4096;
#pragma unroll
        for (int t2 = 0; t2 < 4; ++t2) {
            int e = (t2 * 256 + tid) * 4;
            int y = e >> 6, x0 = e & 63;
            int p = ((y >> 3) << 3) + (x0 >> 3);
            int k = ((y & 7) << 3) + (x0 & 7);
            float4 v = *(const float4*)(plane + e);
            uint32* dst = (uint32*)&As[p * 72 + k];
            dst[0] = cvtpk(v.x, v.y);
            dst[1] = cvtpk(v.z, v.w);
        }
        {
            const float4* s4 = (const float4*)(wsrc + rz * 64);
            uint32* d = (uint32*)&Bs[oc * 72 + hf * 32];
#pragma unroll
            for (int r = 0; r < 8; ++r) {
                float4 v = s4[r];
                d[2 * r]     = cvtpk(v.x, v.y);
                d[2 * r + 1] = cvtpk(v.z, v.w);
            }
        }
        __syncthreads();
#pragma unroll
        for (int ks = 0; ks < 2; ++ks) {
            short8 bb0 = *(const short8*)&Bs[((wv * 2 + 0) * 16 + lc) * 72 + ks * 32 + lg * 8];
            short8 bb1 = *(const short8*)&Bs[((wv * 2 + 1) * 16 + lc) * 72 + ks * 32 + lg * 8];
#pragma unroll
            for (int mt = 0; mt < 4; ++mt) {
                short8 a = *(const short8*)&As[(mt * 16 + lc) * 72 + ks * 32 + lg * 8];
                acc[mt][0] = __builtin_amdgcn_mfma_f32_16x16x32_bf16(a, bb0, acc[mt][0], 0, 0, 0);
                acc[mt][1] = __builtin_amdgcn_mfma_f32_16x16x32_bf16(a, bb1, acc[mt][1], 0, 0, 0);
            }
        }
    }
    // epilogue: bf16 partial[ic][b][pz*64+m][oc]
    unsigned short* pb = partial + (((size_t)ic * 2 + b) * 256 + pz * 64) * 128;
#pragma unroll
    for (int mt = 0; mt < 4; ++mt)
#pragma unroll
        for (int ntl = 0; ntl < 2; ++ntl) {
            int oco = (wv * 2 + ntl) * 16 + lc;
#pragma unroll
            for (int r = 0; r < 4; ++r) {
                int m = mt * 16 + lg * 4 + r;
                pb[(size_t)m * 128 + oco] = bf16r(acc[mt][ntl][r]);
            }
        }
}

// ---------------- K3: reduce bf16 partials over ic (+ folded weight prep) ----------------
__global__ void k_reduce(const unsigned short* __restrict__ partial,
                         const float* __restrict__ wq, const float* __restrict__ wout,
                         unsigned short* __restrict__ kt, unsigned short* __restrict__ vt,
                         unsigned short* __restrict__ wqb, unsigned short* __restrict__ woutb) {
    int gid = blockIdx.x * 256 + threadIdx.x;
    if (gid < 4096) {
        const float QS = 0.36067376022224085f;   // 0.25 * log2(e)
        wqb[gid]   = bf16b(wq[gid] * QS);
        woutb[gid] = bf16b(wout[gid]);
    }
    int oc = gid & 127;
    int bp = gid >> 7;          // b*256 + j
    int b = bp >> 8;
    int j = bp & 255;
    const unsigned short* p = partial + (size_t)bp * 128 + oc;
    float s = 0.f;
#pragma unroll 8
    for (int ic = 0; ic < 64; ++ic)
        s += __builtin_bit_cast(float, (uint32)p[(size_t)ic * 65536] << 16);
    int h = (oc & 63) >> 4, i = oc & 15;
    if (oc < 64) {
        kt[(((size_t)b * 4 + h) * 256 + j) * 16 + i] = bf16b(s);
    } else {
        int q = j & 31;
        int jp = (j & ~31) | (((q & 15) >> 2) * 8 + (q & 3) + ((q >> 4) << 2));
        vt[(((size_t)b * 4 + h) * 16 + i) * 256 + jp] = bf16b(s);
    }
}

// ---------------- K4: R21 attention with single-op truncating P-pack ----------------
__global__ __launch_bounds__(256, 5) void k_attn17(
    const float* __restrict__ x, const unsigned short* __restrict__ wqb,
    const unsigned short* __restrict__ woutb, const unsigned short* __restrict__ kt,
    const unsigned short* __restrict__ vt, float* __restrict__ out)
{
    __shared__ __align__(16) unsigned short s_at[64 * 72];    // x^T then att [n][c]
    __shared__ __align__(16) unsigned short s_q[4][64 * 20];  // per-wave Q [n][i] stride 20

    const int tid = threadIdx.x;
    const int b = blockIdx.x >> 11;
    const int n_base = (blockIdx.x & 2047) << 6;
    const int lane = tid & 63;
    const int wv = tid >> 6;     // head index
    const int lc = lane & 15;
    const int lg = lane >> 4;

    unsigned short* qs = s_q[wv];

    // ---- stage x^T [64][72] cooperatively (verified) ----
    {
        int n_l = tid & 63;
        int c0  = (tid >> 6) * 16;
        const float* xb = x + ((size_t)b << 23) + n_base + n_l;
        uint32* xrow = (uint32*)&s_at[n_l * 72 + c0];
#pragma unroll
        for (int r = 0; r < 8; ++r) {
            float v0 = xb[(size_t)(c0 + 2 * r) << 17];
            float v1 = xb[(size_t)(c0 + 2 * r + 1) << 17];
            xrow[r] = cvtpk(v0, v1);
        }
    }
    __syncthreads();   // B1: x^T staged

    // ---- Q-proj (verified, store stride 20) ----
#pragma unroll
    for (int t = 0; t < 4; ++t) {
        floatx4 c = {0.f, 0.f, 0.f, 0.f};
#pragma unroll
        for (int ks = 0; ks < 2; ++ks) {
            short8 a = *(const short8*)&s_at[(t * 16 + lc) * 72 + ks * 32 + lg * 8];
            short8 bfull;
            __builtin_memcpy(&bfull, wqb + (wv * 16 + lc) * 64 + ks * 32 + lg * 8, 16);
            c = __builtin_amdgcn_mfma_f32_16x16x32_bf16(a, bfull, c, 0, 0, 0);
        }
#pragma unroll
        for (int r = 0; r < 4; ++r)
            qs[(t * 16 + lg * 4 + r) * 20 + lc] = bf16b(c[r]);
    }

    __syncthreads();   // B2: fences transposed Q writes->reads AND Q-proj s_at reads

    // ---- hoist Q B-frags AFTER the barrier: logical k=i=lg*4+e via emb4 ----
    short8 qf[4];
#pragma unroll
    for (int t = 0; t < 4; ++t)
        qf[t] = emb4m(&qs[(t * 16 + lc) * 20 + lg * 4]);

    // ---- head loop: 8 pairs of j-tiles; full-K PV + ones-MFMA denominator ----
    const unsigned short* kbase = kt + (((size_t)b * 4 + wv) << 12) + lc * 16 + lg * 4;
    const unsigned short* vbase = vt + (((size_t)b * 4 + wv) << 12) + lc * 256 + lg * 8;
    const short8 ONES = {(short)0x3F80, (short)0x3F80, (short)0x3F80, (short)0x3F80,
                         (short)0x3F80, (short)0x3F80, (short)0x3F80, (short)0x3F80};
    const floatx4 Z = {0.f, 0.f, 0.f, 0.f};
    floatx4 pv[4], pvl[4];
#pragma unroll
    for (int t = 0; t < 4; ++t) { pv[t] = Z; pvl[t] = Z; }

#pragma unroll
    for (int m = 0; m < 8; ++m) {
        short8 kf0 = emb4m(kbase + m * 512);          // j = m*32 + lc rows
        short8 kf1 = emb4m(kbase + m * 512 + 256);    // j = m*32 + 16 + lc rows
        short8 vf;
        __builtin_memcpy(&vf, vbase + m * 32, 16);    // permuted-j layout
#pragma unroll
        for (int t = 0; t < 4; ++t) {
            floatx4 c0 = __builtin_amdgcn_mfma_f32_16x16x32_bf16(kf0, qf[t], Z, 0, 0, 0); // j=j0+lg*4+r
            floatx4 c1 = __builtin_amdgcn_mfma_f32_16x16x32_bf16(kf1, qf[t], Z, 0, 0, 0); // j=j0+16+lg*4+r
            float p0 = EXP2(c0[0]), p1 = EXP2(c0[1]), p2 = EXP2(c0[2]), p3 = EXP2(c0[3]);
            float p4 = EXP2(c1[0]), p5 = EXP2(c1[1]), p6 = EXP2(c1[2]), p7 = EXP2(c1[3]);
            short8 pa = mk8(pkt(p0, p1), pkt(p2, p3), pkt(p4, p5), pkt(p6, p7));
            pv[t]  = __builtin_amdgcn_mfma_f32_16x16x32_bf16(pa, vf,   pv[t],  0, 0, 0); // att: i=lc, n=lg*4+r
            pvl[t] = __builtin_amdgcn_mfma_f32_16x16x32_bf16(pa, ONES, pvl[t], 0, 0, 0); // l[n] same slot
        }
    }

    // ---- rescale in-lane; cheap-round att -> s_at ----
#pragma unroll
    for (int t = 0; t < 4; ++t) {
#pragma unroll
        for (int r = 0; r < 4; ++r) {
            float rl = RCPF(pvl[t][r]);
            s_at[(t * 16 + lg * 4 + r) * 72 + wv * 16 + lc] = bf16r(pv[t][r] * rl);
        }
    }

    __syncthreads();   // B3: att complete (fences transposed att writes -> reads)

    // ---- out-proj + direct float4 stores: o = wv*16+lc (C col), n = C row ----
#pragma unroll
    for (int t = 0; t < 4; ++t) {
        floatx4 c = {0.f, 0.f, 0.f, 0.f};
#pragma unroll
        for (int ks = 0; ks < 2; ++ks) {
            short8 a = *(const short8*)&s_at[(t * 16 + lc) * 72 + ks * 32 + lg * 8];
            short8 bfull;
            __builtin_memcpy(&bfull, woutb + (wv * 16 + lc) * 64 + ks * 32 + lg * 8, 16);
            c = __builtin_amdgcn_mfma_f32_16x16x32_bf16(a, bfull, c, 0, 0, 0);
        }
        float* dst = out + ((size_t)b << 23) + (size_t)(wv * 16 + lc) * NPOS
                   + n_base + t * 16 + lg * 4;
        *(floatx4*)dst = c;
    }
}

extern "C" void kernel_launch(void* const* d_in, const int* in_sizes, int n_in,
                              void* d_out, int out_size, void* d_ws, size_t ws_size,
                              hipStream_t stream) {
    const float* x    = (const float*)d_in[0];
    const float* wq   = (const float*)d_in[1];
    const float* wkv  = (const float*)d_in[2];
    const float* wout = (const float*)d_in[3];
    float* out = (float*)d_out;
    float* ws = (float*)d_ws;

    unsigned short* partial = (unsigned short*)ws;            // [64][2][256][128] bf16 = 8 MB
    unsigned short* ktu   = (unsigned short*)(ws + 2097152);  // [2][4][256][16] bf16
    unsigned short* vtu   = ktu + 32768;                      // [2][4][16][256] bf16 (j-permuted)
    unsigned short* wqb   = vtu + 32768;                      // [64][64] bf16
    unsigned short* woutb = wqb + 4096;                       // [64][64] bf16

    k_conv_mfma<<<512,  256, 0, stream>>>(x, wkv, partial);
    k_reduce   <<<256,  256, 0, stream>>>(partial, wq, wout, ktu, vtu, wqb, woutb);
    k_attn17   <<<4096, 256, 0, stream>>>(x, wqb, woutb, ktu, vtu, out);
}